// Round 13
// baseline (205.378 us; speedup 1.0000x reference)
//
#include <hip/hip_runtime.h>

#define D_MODEL 1024
#define NH 16
#define DK 64
#define BB 4
#define SS 2048
#define MROWS (BB*SS)

typedef __attribute__((ext_vector_type(4))) float f32x4;
typedef __attribute__((ext_vector_type(16))) float f32x16;
typedef __attribute__((ext_vector_type(8))) short short8;
typedef __attribute__((ext_vector_type(4))) float float4v;
typedef __attribute__((ext_vector_type(2))) unsigned u32x2;

typedef const __attribute__((address_space(1))) void* gas_t;
typedef __attribute__((address_space(3))) void* las_t;

static __device__ __forceinline__ ushort f2bf(float f) {
  union { float f; unsigned u; } v; v.f = f;
  unsigned r = 0x7fffu + ((v.u >> 16) & 1u);
  return (ushort)((v.u + r) >> 16);
}

// counted vmcnt wait + scheduling fence (rule #18)
#define VM_WAIT(N)                                              \
  do {                                                          \
    asm volatile("s_waitcnt vmcnt(" #N ")" ::: "memory");       \
    __builtin_amdgcn_sched_barrier(0);                          \
  } while (0)

#define LGKM0()                                                 \
  do {                                                          \
    asm volatile("s_waitcnt lgkmcnt(0)" ::: "memory");          \
    __builtin_amdgcn_sched_barrier(0);                          \
  } while (0)

// ---------------- convert x (fp32 -> bf16), 4 elems/thread ----------------
__global__ __launch_bounds__(256) void convert_x_k(const float* __restrict__ x,
                                                   ushort* __restrict__ xb) {
  int i = blockIdx.x * 256 + threadIdx.x;
  float4v v = ((const float4v*)x)[i];
  ushort4 o;
  o.x = f2bf(v.x); o.y = f2bf(v.y); o.z = f2bf(v.z); o.w = f2bf(v.w);
  ((ushort4*)xb)[i] = o;
}

// ------- transpose 4 weights [K][N] fp32 -> [N][K] bf16, one launch -------
__global__ __launch_bounds__(256) void convert_wt4_k(const float* __restrict__ w0,
                                                     const float* __restrict__ w1,
                                                     const float* __restrict__ w2,
                                                     const float* __restrict__ w3,
                                                     ushort* __restrict__ t0,
                                                     ushort* __restrict__ t1,
                                                     ushort* __restrict__ t2,
                                                     ushort* __restrict__ t3) {
  __shared__ float tile[64][65];
  const float* w; ushort* wt;
  switch (blockIdx.z) {
    case 0: w = w0; wt = t0; break;
    case 1: w = w1; wt = t1; break;
    case 2: w = w2; wt = t2; break;
    default: w = w3; wt = t3; break;
  }
  int bx = blockIdx.x, by = blockIdx.y;
  int tx = threadIdx.x & 63, ty = threadIdx.x >> 6;
#pragma unroll
  for (int i = 0; i < 16; ++i) {
    int r = i * 4 + ty;
    tile[r][tx] = w[(size_t)(by * 64 + r) * D_MODEL + bx * 64 + tx];
  }
  __syncthreads();
#pragma unroll
  for (int i = 0; i < 16; ++i) {
    int r = i * 4 + ty;
    wt[(size_t)(bx * 64 + r) * D_MODEL + by * 64 + tx] = f2bf(tile[tx][r]);
  }
}

// ===== 256x256-tile 4-phase pipelined GEMM (m201-geometry port) ==========
// BM=BN=256, BK=64, 512 thr = 8 waves (2M x 4N), per-wave 128x64 out.
// LDS: A,B each [2 buf][2 half][128][64] bf16 = 64 KB -> 128 KB total.
// Phase order (race-fixed vs R12): [stage] -> [VM_WAIT(4) at p0] -> barrier
// -> ds_read -> lgkm0 -> setprio 16 MFMA -> trailing barrier.
// Drain-order proof: at tile kt p0 after issuing B(kt+1)x4, the only <=4
// outstanding loads are B(kt+1) -> B(kt),A0(kt),A1(kt) landed before any
// read. Phase-3 trailing barrier protects buffer swap. vmcnt never 0 midloop.
// chunk-XOR swizzle (pos = chunk ^ (row&7)) on source AND read (0 conflicts).
template <int MODE>
__global__ __launch_bounds__(512) void gemm256_k(const ushort* __restrict__ A,
                                                 const ushort* __restrict__ Bt,
                                                 const float* __restrict__ b0,
                                                 const float* __restrict__ b1,
                                                 const float* __restrict__ b2,
                                                 ushort* __restrict__ Qw,
                                                 ushort* __restrict__ Kw,
                                                 ushort* __restrict__ Vw,
                                                 float* __restrict__ Fo,
                                                 float qscale) {
  __shared__ __align__(16) ushort AsS[2][2][8192];   // [buf][half][128*64]
  __shared__ __align__(16) ushort BsS[2][2][8192];
  const int bid = blockIdx.x;
  const int xcd = bid & 7, i0 = bid >> 3;
  const int bm = xcd * 4 + (i0 & 3);      // 4 disjoint A-panels per XCD
  const int bn = i0 >> 2;                 // qkv: 0..11, out: 0..3
  const int t = threadIdx.x;
  const int l = t & 63;
  const int w = t >> 6;                   // 0..7
  const int g = l >> 4, q = l & 15;
  const int wr = w >> 2;                  // 0..1 : M-warp -> A-half
  const int wc = w & 3;                   // 0..3 : N-warp (64-col slice)
  const int qs = q & 7;

  f32x4 acc[8][4];
#pragma unroll
  for (int m = 0; m < 8; ++m)
#pragma unroll
    for (int n = 0; n < 4; ++n) acc[m][n] = f32x4{0.f, 0.f, 0.f, 0.f};

  const ushort* Ab = A + (size_t)bm * 256 * D_MODEL;
  const ushort* Bb = Bt + (size_t)bn * 256 * D_MODEL;

// stage one half-tile (128 rows x 64 cols) of operand into [BUFI][HF]
#define STG(PS, SRC, BUFI, HF, T)                                                             \
  do {                                                                                        \
    _Pragma("unroll") for (int s_ = 0; s_ < 2; ++s_) {                                        \
      int c_ = s_ * 512 + t;                                                                  \
      int r_ = c_ >> 3;                                                                       \
      int gc_ = (c_ & 7) ^ (r_ & 7);                                                          \
      __builtin_amdgcn_global_load_lds(                                                       \
          (gas_t)(SRC + (size_t)((HF) * 128 + r_) * D_MODEL + (T) * 64 + gc_ * 8),            \
          (las_t)(&PS[BUFI][HF][c_ * 8]), 16, 0, 0);                                          \
    }                                                                                         \
  } while (0)

  const int NT = 16;                       // K=1024 / BK=64
  // prologue: tile 0 fully staged into buf 0 (8 loads)
  STG(BsS, Bb, 0, 0, 0); STG(BsS, Bb, 0, 1, 0);
  STG(AsS, Ab, 0, 0, 0); STG(AsS, Ab, 0, 1, 0);

  for (int kt = 0; kt < NT; ++kt) {
    const int buf = kt & 1, nbuf = buf ^ 1;
    const bool st = (kt + 1) < NT;
    const ushort* Ah = AsS[buf][wr];       // this wave's A-half
    const ushort* Bh = BsS[buf][wc >> 1];
    const int brow = (wc & 1) * 64;
    short8 bf[4], af[4];

    // ---- phase 0: stage B0,B1(T+1); wait; publish; (mh0,ks0) ----
    if (st) { STG(BsS, Bb, nbuf, 0, kt + 1); STG(BsS, Bb, nbuf, 1, kt + 1); VM_WAIT(4); }
    else { VM_WAIT(0); }
    __builtin_amdgcn_s_barrier();
#pragma unroll
    for (int n = 0; n < 4; ++n)
      bf[n] = *(const short8*)(Bh + (brow + n * 16 + q) * 64 + ((g ^ qs) * 8));
#pragma unroll
    for (int m2 = 0; m2 < 4; ++m2)
      af[m2] = *(const short8*)(Ah + (m2 * 16 + q) * 64 + ((g ^ qs) * 8));
    LGKM0();
    __builtin_amdgcn_s_setprio(1);
#pragma unroll
    for (int m2 = 0; m2 < 4; ++m2)
#pragma unroll
      for (int n = 0; n < 4; ++n)
        acc[m2][n] = __builtin_amdgcn_mfma_f32_16x16x32_bf16(af[m2], bf[n], acc[m2][n], 0, 0, 0);
    __builtin_amdgcn_s_setprio(0);
    __builtin_amdgcn_s_barrier();

    // ---- phase 1: (mh1,ks0), bf reused; stage A0(T+1) ----
#pragma unroll
    for (int m2 = 0; m2 < 4; ++m2)
      af[m2] = *(const short8*)(Ah + (64 + m2 * 16 + q) * 64 + ((g ^ qs) * 8));
    if (st) STG(AsS, Ab, nbuf, 0, kt + 1);
    LGKM0();
    __builtin_amdgcn_s_setprio(1);
#pragma unroll
    for (int m2 = 0; m2 < 4; ++m2)
#pragma unroll
      for (int n = 0; n < 4; ++n)
        acc[4 + m2][n] = __builtin_amdgcn_mfma_f32_16x16x32_bf16(af[m2], bf[n], acc[4 + m2][n], 0, 0, 0);
    __builtin_amdgcn_s_setprio(0);
    __builtin_amdgcn_s_barrier();

    // ---- phase 2: (mh0,ks1); stage A1(T+1) ----
#pragma unroll
    for (int n = 0; n < 4; ++n)
      bf[n] = *(const short8*)(Bh + (brow + n * 16 + q) * 64 + (((4 + g) ^ qs) * 8));
#pragma unroll
    for (int m2 = 0; m2 < 4; ++m2)
      af[m2] = *(const short8*)(Ah + (m2 * 16 + q) * 64 + (((4 + g) ^ qs) * 8));
    if (st) STG(AsS, Ab, nbuf, 1, kt + 1);
    LGKM0();
    __builtin_amdgcn_s_setprio(1);
#pragma unroll
    for (int m2 = 0; m2 < 4; ++m2)
#pragma unroll
      for (int n = 0; n < 4; ++n)
        acc[m2][n] = __builtin_amdgcn_mfma_f32_16x16x32_bf16(af[m2], bf[n], acc[m2][n], 0, 0, 0);
    __builtin_amdgcn_s_setprio(0);
    __builtin_amdgcn_s_barrier();

    // ---- phase 3: (mh1,ks1), bf reused ----
#pragma unroll
    for (int m2 = 0; m2 < 4; ++m2)
      af[m2] = *(const short8*)(Ah + (64 + m2 * 16 + q) * 64 + (((4 + g) ^ qs) * 8));
    LGKM0();
    __builtin_amdgcn_s_setprio(1);
#pragma unroll
    for (int m2 = 0; m2 < 4; ++m2)
#pragma unroll
      for (int n = 0; n < 4; ++n)
        acc[4 + m2][n] = __builtin_amdgcn_mfma_f32_16x16x32_bf16(af[m2], bf[n], acc[4 + m2][n], 0, 0, 0);
    __builtin_amdgcn_s_setprio(0);
    __builtin_amdgcn_s_barrier();       // all reads of buf done -> safe to overwrite next kt
  }
#undef STG

  // ---- epilogue ----
  if (MODE == 1) {
#pragma unroll
    for (int mf = 0; mf < 8; ++mf) {
      int r0 = bm * 256 + wr * 128 + mf * 16 + g * 4;
#pragma unroll
      for (int nf = 0; nf < 4; ++nf) {
        int c = bn * 256 + wc * 64 + nf * 16 + q;
        float bv = b0[c];
#pragma unroll
        for (int j = 0; j < 4; ++j)
          Fo[(size_t)(r0 + j) * D_MODEL + c] = acc[mf][nf][j] + bv;
      }
    }
  } else {
    const int sec = (bn * 256) >> 10;            // 0=Q 1=K 2=V (256 | 1024)
    const float* bias = sec == 0 ? b0 : (sec == 1 ? b1 : b2);
    const float scale = sec == 0 ? qscale : 1.0f;
    ushort* dst = sec == 0 ? Qw : Kw;
#pragma unroll
    for (int mf = 0; mf < 8; ++mf) {
      int r0 = bm * 256 + wr * 128 + mf * 16 + g * 4;
#pragma unroll
      for (int nf = 0; nf < 4; ++nf) {
        int cg_ = bn * 256 + wc * 64 + nf * 16 + q;
        int c = cg_ & 1023;
        float bv_ = bias[c];
        if (sec == 2) {
          ushort4 pk;
          pk.x = f2bf(acc[mf][nf][0] + bv_);
          pk.y = f2bf(acc[mf][nf][1] + bv_);
          pk.z = f2bf(acc[mf][nf][2] + bv_);
          pk.w = f2bf(acc[mf][nf][3] + bv_);
          size_t off = (((size_t)((r0 >> 11) * NH + (c >> 6))) * DK + (c & 63)) * (size_t)SS + (r0 & (SS - 1));
          *(ushort4*)(Vw + off) = pk;
        } else {
#pragma unroll
          for (int j = 0; j < 4; ++j) {
            int r = r0 + j;
            float v = (acc[mf][nf][j] + bv_) * scale;
            size_t off = (((size_t)((r >> 11) * NH + (c >> 6))) * SS + (r & (SS - 1))) * DK + (c & 63);
            dst[off] = f2bf(v);
          }
        }
      }
    }
  }
}

// ---------------- flash attention (R8-exact, best measured) ---------------
__global__ __launch_bounds__(256, 4) void attn_k(const ushort* __restrict__ Qm,
                                                 const ushort* __restrict__ Km,
                                                 const ushort* __restrict__ Vm,
                                                 ushort* __restrict__ Ob) {
  __shared__ __align__(16) ushort Ks[2][64 * 64];
  __shared__ __align__(16) ushort Vs[2][64 * 64];
  const int bid = blockIdx.x;
  const int logical = (bid & 7) * 128 + (bid >> 3);
  const int bh = logical >> 4;
  const int qblk = logical & 15;
  const int t = threadIdx.x, l = t & 63, w = t >> 6;
  const int q = l & 31, h = l >> 5;
  const int qsw = q & 7;

  const ushort* Qb = Qm + ((size_t)bh * SS + qblk * 128 + w * 32) * DK;
  const ushort* Kb = Km + (size_t)bh * SS * DK;
  const ushort* Vb = Vm + (size_t)bh * DK * SS;

  short8 qf[4];
#pragma unroll
  for (int ks = 0; ks < 4; ++ks)
    qf[ks] = *(const short8*)(Qb + q * DK + ks * 16 + h * 8);

  f32x16 oacc[2];
#pragma unroll
  for (int d = 0; d < 2; ++d)
#pragma unroll
    for (int r = 0; r < 16; ++r) oacc[d][r] = 0.f;
  float lrun = 0.f;

  const int cg = (l & 7) ^ ((l >> 3) & 7);

#define STAGE(B, KT)                                                                        \
  do {                                                                                      \
    _Pragma("unroll") for (int i_ = 0; i_ < 2; ++i_) {                                      \
      int row_ = w * 16 + i_ * 8 + (l >> 3);                                                \
      __builtin_amdgcn_global_load_lds((gas_t)(Kb + (size_t)((KT) + row_) * DK + cg * 8),   \
                                       (las_t)(Ks[B] + (w * 16 + i_ * 8) * 64 + l * 8),     \
                                       16, 0, 0);                                           \
      __builtin_amdgcn_global_load_lds((gas_t)(Vb + (size_t)row_ * SS + (KT) + cg * 8),     \
                                       (las_t)(Vs[B] + (w * 16 + i_ * 8) * 64 + l * 8),     \
                                       16, 0, 0);                                           \
    }                                                                                       \
  } while (0)

  STAGE(0, 0);
  int cur = 0;

  for (int kt = 0; kt < SS; kt += 64) {
    __syncthreads();
    if (kt + 64 < SS) STAGE(cur ^ 1, kt + 64);

    const ushort* Kc = Ks[cur];
    const ushort* Vc = Vs[cur];

    f32x16 sc[2];
#pragma unroll
    for (int n = 0; n < 2; ++n)
#pragma unroll
      for (int r = 0; r < 16; ++r) sc[n][r] = 0.f;

    __builtin_amdgcn_s_setprio(1);
#pragma unroll
    for (int ks = 0; ks < 4; ++ks) {
      int ch = ((ks * 2 + h) ^ qsw) * 8;
      short8 kf0 = *(const short8*)(Kc + q * 64 + ch);
      short8 kf1 = *(const short8*)(Kc + (32 + q) * 64 + ch);
      sc[0] = __builtin_amdgcn_mfma_f32_32x32x16_bf16(kf0, qf[ks], sc[0], 0, 0, 0);
      sc[1] = __builtin_amdgcn_mfma_f32_32x32x16_bf16(kf1, qf[ks], sc[1], 0, 0, 0);
    }
    __builtin_amdgcn_s_setprio(0);

#pragma unroll
    for (int n = 0; n < 2; ++n)
#pragma unroll
      for (int r = 0; r < 16; ++r) sc[n][r] = __builtin_amdgcn_exp2f(sc[n][r]);

    float s8[8];
#pragma unroll
    for (int i = 0; i < 8; ++i)
      s8[i] = (sc[0][i] + sc[0][i + 8]) + (sc[1][i] + sc[1][i + 8]);
#pragma unroll
    for (int i = 0; i < 4; ++i) s8[i] += s8[i + 4];
    lrun += (s8[0] + s8[1]) + (s8[2] + s8[3]);

    short8 pf[4];
#pragma unroll
    for (int n = 0; n < 2; ++n) {
      unsigned wv[8];
#pragma unroll
      for (int Qd = 0; Qd < 4; ++Qd) {
        unsigned w0, w1;
        asm("v_cvt_pk_bf16_f32 %0, %1, %2" : "=v"(w0) : "v"(sc[n][Qd * 4 + 0]), "v"(sc[n][Qd * 4 + 1]));
        asm("v_cvt_pk_bf16_f32 %0, %1, %2" : "=v"(w1) : "v"(sc[n][Qd * 4 + 2]), "v"(sc[n][Qd * 4 + 3]));
        wv[Qd * 2] = w0; wv[Qd * 2 + 1] = w1;
      }
#pragma unroll
      for (int m = 0; m < 2; ++m) {
        u32x2 r0 = __builtin_amdgcn_permlane32_swap(wv[(2 * m) * 2 + 0], wv[(2 * m + 1) * 2 + 0], false, false);
        u32x2 r1 = __builtin_amdgcn_permlane32_swap(wv[(2 * m) * 2 + 1], wv[(2 * m + 1) * 2 + 1], false, false);
        union { unsigned u[4]; short8 s; } fu;
        fu.u[0] = r0[0]; fu.u[1] = r1[0]; fu.u[2] = r0[1]; fu.u[3] = r1[1];
        pf[n * 2 + m] = fu.s;
      }
    }

    __builtin_amdgcn_s_setprio(1);
#pragma unroll
    for (int kvb = 0; kvb < 4; ++kvb) {
      int ch = ((kvb * 2 + h) ^ qsw) * 8;
      short8 vf0 = *(const short8*)(Vc + q * 64 + ch);
      short8 vf1 = *(const short8*)(Vc + (32 + q) * 64 + ch);
      oacc[0] = __builtin_amdgcn_mfma_f32_32x32x16_bf16(vf0, pf[kvb], oacc[0], 0, 0, 0);
      oacc[1] = __builtin_amdgcn_mfma_f32_32x32x16_bf16(vf1, pf[kvb], oacc[1], 0, 0, 0);
    }
    __builtin_amdgcn_s_setprio(0);
    cur ^= 1;
  }
#undef STAGE

  const int b_ = bh >> 4, h_ = bh & 15;
  float lt = lrun;
  lt += __shfl_xor(lt, 32);
  float inv = 1.0f / lt;
  const int srow = qblk * 128 + w * 32 + q;
#pragma unroll
  for (int d = 0; d < 2; ++d)
#pragma unroll
    for (int rq = 0; rq < 4; ++rq) {
      ushort4 pk;
      pk.x = f2bf(oacc[d][rq * 4 + 0] * inv);
      pk.y = f2bf(oacc[d][rq * 4 + 1] * inv);
      pk.z = f2bf(oacc[d][rq * 4 + 2] * inv);
      pk.w = f2bf(oacc[d][rq * 4 + 3] * inv);
      size_t off = ((size_t)b_ * SS + srow) * D_MODEL + h_ * 64 + d * 32 + rq * 8 + h * 4;
      *(ushort4*)(Ob + off) = pk;
    }
}

extern "C" void kernel_launch(void* const* d_in, const int* in_sizes, int n_in,
                              void* d_out, int out_size, void* d_ws, size_t ws_size,
                              hipStream_t stream) {
  (void)in_sizes; (void)n_in; (void)out_size; (void)ws_size;
  const float* x  = (const float*)d_in[0];
  const float* wq = (const float*)d_in[1];
  const float* bq = (const float*)d_in[2];
  const float* wk = (const float*)d_in[3];
  const float* bk = (const float*)d_in[4];
  const float* wv = (const float*)d_in[5];
  const float* bv = (const float*)d_in[6];
  const float* wo = (const float*)d_in[7];
  const float* bo = (const float*)d_in[8];

  char* ws = (char*)d_ws;
  // layout (bytes): xb 16MB | wqkvt 6MB | wot 2MB | Qw 16MB | Kw 16MB | Vw 16MB
  ushort* xb    = (ushort*)(ws);
  ushort* wqkvt = (ushort*)(ws + 16777216);
  ushort* wot   = (ushort*)(ws + 16777216 + 6291456);
  ushort* Qw    = (ushort*)(ws + 16777216 + 6291456 + 2097152);
  ushort* Kw    = (ushort*)(ws + 16777216 + 6291456 + 2097152 + 16777216);
  ushort* Vw    = (ushort*)(ws + 16777216 + 6291456 + 2097152 + 2 * 16777216);
  ushort* Obw   = xb;  // xb dead after QKV projection; reuse for attention output

  convert_x_k<<<MROWS * D_MODEL / 4 / 256, 256, 0, stream>>>(x, xb);
  convert_wt4_k<<<dim3(16, 16, 4), 256, 0, stream>>>(
      wq, wk, wv, wo, wqkvt, wqkvt + 1024 * 1024, wqkvt + 2 * 1024 * 1024, wot);

  // Q pre-scaled by (1/sqrt(DK)) * log2(e) so softmax runs in exp2 domain
  gemm256_k<0><<<384, 512, 0, stream>>>(xb, wqkvt, bq, bk, bv, Qw, Kw, Vw, nullptr,
                                        0.125f * 1.44269504088896f);

  attn_k<<<1024, 256, 0, stream>>>(Qw, Kw, Vw, Obw);

  gemm256_k<1><<<128, 512, 0, stream>>>(Obw, wot, bo, nullptr, nullptr,
                                        nullptr, nullptr, nullptr, (float*)d_out, 1.0f);
}

// Round 14
// 195.712 us; speedup vs baseline: 1.0494x; 1.0494x over previous
//
#include <hip/hip_runtime.h>

#define D_MODEL 1024
#define NH 16
#define DK 64
#define BB 4
#define SS 2048
#define MROWS (BB*SS)

typedef __attribute__((ext_vector_type(4))) float f32x4;
typedef __attribute__((ext_vector_type(16))) float f32x16;
typedef __attribute__((ext_vector_type(8))) short short8;
typedef __attribute__((ext_vector_type(4))) float float4v;
typedef __attribute__((ext_vector_type(2))) unsigned u32x2;

typedef const __attribute__((address_space(1))) void* gas_t;
typedef __attribute__((address_space(3))) void* las_t;

static __device__ __forceinline__ ushort f2bf(float f) {
  union { float f; unsigned u; } v; v.f = f;
  unsigned r = 0x7fffu + ((v.u >> 16) & 1u);
  return (ushort)((v.u + r) >> 16);
}

// counted vmcnt wait + scheduling fence (rule #18)
#define VM_WAIT(N)                                              \
  do {                                                          \
    asm volatile("s_waitcnt vmcnt(" #N ")" ::: "memory");       \
    __builtin_amdgcn_sched_barrier(0);                          \
  } while (0)

#define LGKM0()                                                 \
  do {                                                          \
    asm volatile("s_waitcnt lgkmcnt(0)" ::: "memory");          \
    __builtin_amdgcn_sched_barrier(0);                          \
  } while (0)

// ---------------- convert x (fp32 -> bf16), 4 elems/thread ----------------
__global__ __launch_bounds__(256) void convert_x_k(const float* __restrict__ x,
                                                   ushort* __restrict__ xb) {
  int i = blockIdx.x * 256 + threadIdx.x;
  float4v v = ((const float4v*)x)[i];
  ushort4 o;
  o.x = f2bf(v.x); o.y = f2bf(v.y); o.z = f2bf(v.z); o.w = f2bf(v.w);
  ((ushort4*)xb)[i] = o;
}

// ------- transpose 4 weights [K][N] fp32 -> [N][K] bf16, one launch -------
__global__ __launch_bounds__(256) void convert_wt4_k(const float* __restrict__ w0,
                                                     const float* __restrict__ w1,
                                                     const float* __restrict__ w2,
                                                     const float* __restrict__ w3,
                                                     ushort* __restrict__ t0,
                                                     ushort* __restrict__ t1,
                                                     ushort* __restrict__ t2,
                                                     ushort* __restrict__ t3) {
  __shared__ float tile[64][65];
  const float* w; ushort* wt;
  switch (blockIdx.z) {
    case 0: w = w0; wt = t0; break;
    case 1: w = w1; wt = t1; break;
    case 2: w = w2; wt = t2; break;
    default: w = w3; wt = t3; break;
  }
  int bx = blockIdx.x, by = blockIdx.y;
  int tx = threadIdx.x & 63, ty = threadIdx.x >> 6;
#pragma unroll
  for (int i = 0; i < 16; ++i) {
    int r = i * 4 + ty;
    tile[r][tx] = w[(size_t)(by * 64 + r) * D_MODEL + bx * 64 + tx];
  }
  __syncthreads();
#pragma unroll
  for (int i = 0; i < 16; ++i) {
    int r = i * 4 + ty;
    wt[(size_t)(bx * 64 + r) * D_MODEL + by * 64 + tx] = f2bf(tile[tx][r]);
  }
}

// ------------- fused QKV GEMM: [8192,1024] x [3072,1024]^T ---------------
// 256x128 tile, BK=64, 512 thr (8 waves, 4M x 2N, 64x64 out each).
// 3-buffer LDS, 2-tile-deep prefetch, counted vmcnt (never 0 mid-loop),
// chunk-XOR swizzle (pos = chunk ^ (row&7)) on source AND read -> 0 conflicts.
__global__ __launch_bounds__(512) void gemm_qkv_k(const ushort* __restrict__ A,
                                                  const ushort* __restrict__ Bt,
                                                  const float* __restrict__ bq,
                                                  const float* __restrict__ bk,
                                                  const float* __restrict__ bv,
                                                  ushort* __restrict__ Qw,
                                                  ushort* __restrict__ Kw,
                                                  ushort* __restrict__ Vw,
                                                  float qscale) {
  const int K = D_MODEL;
  __shared__ __align__(16) ushort As[3][256 * 64];   // 3 x 32 KB
  __shared__ __align__(16) ushort Bs[3][128 * 64];   // 3 x 16 KB
  const int nbn = 24;                     // 3072/128
  int bid = blockIdx.x;
  int wg = (bid & 7) * 96 + (bid >> 3);   // XCD swizzle (768 = 8*96, bijective)
  int bm = wg / nbn, bn = wg % nbn;       // bm-major per XCD: A-panel in L2
  const int t = threadIdx.x;
  const int l = t & 63;
  const int w = t >> 6;                   // 0..7
  const int g = l >> 4, q = l & 15;
  const int wr = w >> 1, wc = w & 1;      // 4 M-warps x 2 N-warps
  const int qs = q & 7;

  f32x4 acc[4][4];
#pragma unroll
  for (int m = 0; m < 4; ++m)
#pragma unroll
    for (int n = 0; n < 4; ++n) acc[m][n] = f32x4{0.f, 0.f, 0.f, 0.f};

  const ushort* Ab = A + (size_t)bm * 256 * K;
  const ushort* Bb = Bt + (size_t)bn * 128 * K;

#define GSTAGE(BUF, KT)                                                                       \
  do {                                                                                        \
    _Pragma("unroll") for (int i_ = 0; i_ < 4; ++i_) {                                        \
      int c_ = i_ * 512 + t;                                                                  \
      int r_ = c_ >> 3;                                                                       \
      int gc_ = (c_ & 7) ^ (r_ & 7);                                                          \
      __builtin_amdgcn_global_load_lds((gas_t)(Ab + (size_t)r_ * K + (KT) * 64 + gc_ * 8),    \
                                       (las_t)(&As[BUF][c_ * 8]), 16, 0, 0);                  \
    }                                                                                         \
    _Pragma("unroll") for (int i_ = 0; i_ < 2; ++i_) {                                        \
      int c_ = i_ * 512 + t;                                                                  \
      int r_ = c_ >> 3;                                                                       \
      int gc_ = (c_ & 7) ^ (r_ & 7);                                                          \
      __builtin_amdgcn_global_load_lds((gas_t)(Bb + (size_t)r_ * K + (KT) * 64 + gc_ * 8),    \
                                       (las_t)(&Bs[BUF][c_ * 8]), 16, 0, 0);                  \
    }                                                                                         \
  } while (0)

  GSTAGE(0, 0);
  GSTAGE(1, 1);

  for (int kt = 0; kt < 16; ++kt) {
    if (kt + 2 < 16) {
      GSTAGE((kt + 2) % 3, kt + 2);
      VM_WAIT(12);                     // t+1, t+2 in flight; tile kt landed
    } else if (kt + 1 < 16) {
      VM_WAIT(6);
    } else {
      VM_WAIT(0);
    }
    __builtin_amdgcn_s_barrier();
    __builtin_amdgcn_sched_barrier(0);

    const ushort* Ac = As[kt % 3];
    const ushort* Bc = Bs[kt % 3];

    short8 bf[4][2];
#pragma unroll
    for (int n = 0; n < 4; ++n)
#pragma unroll
      for (int ks = 0; ks < 2; ++ks)
        bf[n][ks] = *(const short8*)(Bc + (wc * 64 + n * 16 + q) * 64 + (((ks * 4 + g) ^ qs) * 8));

#pragma unroll
    for (int mh = 0; mh < 2; ++mh) {
      short8 af[2][2];
#pragma unroll
      for (int m2 = 0; m2 < 2; ++m2)
#pragma unroll
        for (int ks = 0; ks < 2; ++ks)
          af[m2][ks] = *(const short8*)(Ac + (wr * 64 + (mh * 2 + m2) * 16 + q) * 64 + (((ks * 4 + g) ^ qs) * 8));
      LGKM0();
      __builtin_amdgcn_s_setprio(1);
#pragma unroll
      for (int m2 = 0; m2 < 2; ++m2)
#pragma unroll
        for (int n = 0; n < 4; ++n)
#pragma unroll
          for (int ks = 0; ks < 2; ++ks)
            acc[mh * 2 + m2][n] =
                __builtin_amdgcn_mfma_f32_16x16x32_bf16(af[m2][ks], bf[n][ks], acc[mh * 2 + m2][n], 0, 0, 0);
      __builtin_amdgcn_s_setprio(0);
    }

    __builtin_amdgcn_sched_barrier(0);
    __builtin_amdgcn_s_barrier();      // protect buf[(kt+3)%3] == buf[kt%3] restage
  }
#undef GSTAGE

  const int sec = (bn * 128) >> 10;            // 0=Q 1=K 2=V
  const float* bias = sec == 0 ? bq : (sec == 1 ? bk : bv);
  const float scale = sec == 0 ? qscale : 1.0f;
  ushort* dst = sec == 0 ? Qw : Kw;
  const int rbase0 = bm * 256 + wr * 64 + g * 4;
  const int cbase = (bn * 128 + wc * 64 + q) & 1023;
#pragma unroll
  for (int m = 0; m < 4; ++m) {
    int r0 = rbase0 + m * 16;
#pragma unroll
    for (int n = 0; n < 4; ++n) {
      int c = cbase + n * 16;
      float bv_ = bias[c];
      if (sec == 2) {
        ushort4 pk;
        pk.x = f2bf(acc[m][n][0] + bv_);
        pk.y = f2bf(acc[m][n][1] + bv_);
        pk.z = f2bf(acc[m][n][2] + bv_);
        pk.w = f2bf(acc[m][n][3] + bv_);
        size_t off = (((size_t)((r0 >> 11) * NH + (c >> 6))) * DK + (c & 63)) * (size_t)SS + (r0 & (SS - 1));
        *(ushort4*)(Vw + off) = pk;
      } else {
#pragma unroll
        for (int j = 0; j < 4; ++j) {
          int r = r0 + j;
          float v = (acc[m][n][j] + bv_) * scale;
          size_t off = (((size_t)((r >> 11) * NH + (c >> 6))) * SS + (r & (SS - 1))) * DK + (c & 63);
          dst[off] = f2bf(v);
        }
      }
    }
  }
}

// ------------- output GEMM: [8192,1024] x [1024,1024]^T -> fp32 ----------
__global__ __launch_bounds__(256) void gemm_out_k(const ushort* __restrict__ A,
                                                  const ushort* __restrict__ Bt,
                                                  const float* __restrict__ bias,
                                                  float* __restrict__ outp) {
  const int K = D_MODEL;
  __shared__ __align__(16) ushort As[2][128 * 32];
  __shared__ __align__(16) ushort Bs[2][128 * 32];
  const int nbn = 8;
  int bid = blockIdx.x;
  int wg = (bid & 7) * 64 + (bid >> 3);
  int bm = wg / nbn, bn = wg % nbn;
  const int t = threadIdx.x;
  const int l = t & 63;
  const int w = t >> 6;
  const int g = l >> 4, q = l & 15;
  const int wr = w >> 1, wc = w & 1;

  f32x4 acc[4][4];
#pragma unroll
  for (int m = 0; m < 4; ++m)
#pragma unroll
    for (int n = 0; n < 4; ++n) acc[m][n] = f32x4{0.f, 0.f, 0.f, 0.f};

  const ushort* Ab = A + (size_t)bm * 128 * K;
  const ushort* Bb = Bt + (size_t)bn * 128 * K;

#define GSTAGE(BUF, KT)                                                                      \
  do {                                                                                       \
    _Pragma("unroll") for (int i_ = 0; i_ < 2; ++i_) {                                       \
      int c_ = i_ * 256 + t;                                                                 \
      __builtin_amdgcn_global_load_lds((gas_t)(Ab + (size_t)(c_ >> 2) * K + (KT) + (c_ & 3) * 8), \
                                       (las_t)(As[BUF] + c_ * 8), 16, 0, 0);                 \
      __builtin_amdgcn_global_load_lds((gas_t)(Bb + (size_t)(c_ >> 2) * K + (KT) + (c_ & 3) * 8), \
                                       (las_t)(Bs[BUF] + c_ * 8), 16, 0, 0);                 \
    }                                                                                        \
  } while (0)

  GSTAGE(0, 0);
  int cur = 0;

  for (int kt = 0; kt < K; kt += 32) {
    if (kt + 32 < K) {
      GSTAGE(cur ^ 1, kt + 32);
      VM_WAIT(4);
    } else {
      VM_WAIT(0);
    }
    __builtin_amdgcn_s_barrier();
    __builtin_amdgcn_sched_barrier(0);
    short8 af[4], bf[4];
#pragma unroll
    for (int m = 0; m < 4; ++m)
      af[m] = *(const short8*)(As[cur] + (wr * 64 + m * 16 + q) * 32 + g * 8);
#pragma unroll
    for (int n = 0; n < 4; ++n)
      bf[n] = *(const short8*)(Bs[cur] + (wc * 64 + n * 16 + q) * 32 + g * 8);
#pragma unroll
    for (int m = 0; m < 4; ++m)
#pragma unroll
      for (int n = 0; n < 4; ++n)
        acc[m][n] = __builtin_amdgcn_mfma_f32_16x16x32_bf16(af[m], bf[n], acc[m][n], 0, 0, 0);
    __builtin_amdgcn_sched_barrier(0);
    __builtin_amdgcn_s_barrier();
    cur ^= 1;
  }
#undef GSTAGE

  const int rbase0 = bm * 128 + wr * 64 + g * 4;
  const int cbase = bn * 128 + wc * 64 + q;
#pragma unroll
  for (int m = 0; m < 4; ++m) {
    int r0 = rbase0 + m * 16;
#pragma unroll
    for (int n = 0; n < 4; ++n) {
      int c = cbase + n * 16;
      float bv = bias[c];
#pragma unroll
      for (int j = 0; j < 4; ++j)
        outp[(size_t)(r0 + j) * D_MODEL + c] = acc[m][n][j] + bv;
    }
  }
}

// ---------------- flash attention, 32x32 swapped-operand, 32q/wave --------
__global__ __launch_bounds__(256, 4) void attn_k(const ushort* __restrict__ Qm,
                                                 const ushort* __restrict__ Km,
                                                 const ushort* __restrict__ Vm,
                                                 ushort* __restrict__ Ob) {
  __shared__ __align__(16) ushort Ks[2][64 * 64];   // [buf][kv][dk] chunk-XOR-swizzled
  __shared__ __align__(16) ushort Vs[2][64 * 64];   // [buf][d][kv]  chunk-XOR-swizzled
  const int bid = blockIdx.x;
  const int logical = (bid & 7) * 128 + (bid >> 3); // XCD chunk swizzle (1024 = 8*128)
  const int bh = logical >> 4;       // 0..63
  const int qblk = logical & 15;     // 0..15 (128 q-rows/block, 32/wave)
  const int t = threadIdx.x, l = t & 63, w = t >> 6;
  const int q = l & 31, h = l >> 5;
  const int qsw = q & 7;

  const ushort* Qb = Qm + ((size_t)bh * SS + qblk * 128 + w * 32) * DK;
  const ushort* Kb = Km + (size_t)bh * SS * DK;
  const ushort* Vb = Vm + (size_t)bh * DK * SS;

  short8 qf[4];
#pragma unroll
  for (int ks = 0; ks < 4; ++ks)
    qf[ks] = *(const short8*)(Qb + q * DK + ks * 16 + h * 8);

  f32x16 oacc[2];
#pragma unroll
  for (int d = 0; d < 2; ++d)
#pragma unroll
    for (int r = 0; r < 16; ++r) oacc[d][r] = 0.f;
  float lrun = 0.f;

  const int cg = (l & 7) ^ ((l >> 3) & 7);

#define STAGE(B, KT)                                                                        \
  do {                                                                                      \
    _Pragma("unroll") for (int i_ = 0; i_ < 2; ++i_) {                                      \
      int row_ = w * 16 + i_ * 8 + (l >> 3);                                                \
      __builtin_amdgcn_global_load_lds((gas_t)(Kb + (size_t)((KT) + row_) * DK + cg * 8),   \
                                       (las_t)(Ks[B] + (w * 16 + i_ * 8) * 64 + l * 8),     \
                                       16, 0, 0);                                           \
      __builtin_amdgcn_global_load_lds((gas_t)(Vb + (size_t)row_ * SS + (KT) + cg * 8),     \
                                       (las_t)(Vs[B] + (w * 16 + i_ * 8) * 64 + l * 8),     \
                                       16, 0, 0);                                           \
    }                                                                                       \
  } while (0)

  STAGE(0, 0);
  int cur = 0;

  for (int kt = 0; kt < SS; kt += 64) {
    __syncthreads();
    if (kt + 64 < SS) STAGE(cur ^ 1, kt + 64);

    const ushort* Kc = Ks[cur];
    const ushort* Vc = Vs[cur];

    f32x16 sc[2];
#pragma unroll
    for (int n = 0; n < 2; ++n)
#pragma unroll
      for (int r = 0; r < 16; ++r) sc[n][r] = 0.f;

    __builtin_amdgcn_s_setprio(1);
#pragma unroll
    for (int ks = 0; ks < 4; ++ks) {
      int ch = ((ks * 2 + h) ^ qsw) * 8;
      short8 kf0 = *(const short8*)(Kc + q * 64 + ch);
      short8 kf1 = *(const short8*)(Kc + (32 + q) * 64 + ch);
      sc[0] = __builtin_amdgcn_mfma_f32_32x32x16_bf16(kf0, qf[ks], sc[0], 0, 0, 0);
      sc[1] = __builtin_amdgcn_mfma_f32_32x32x16_bf16(kf1, qf[ks], sc[1], 0, 0, 0);
    }
    __builtin_amdgcn_s_setprio(0);

#pragma unroll
    for (int n = 0; n < 2; ++n)
#pragma unroll
      for (int r = 0; r < 16; ++r) sc[n][r] = __builtin_amdgcn_exp2f(sc[n][r]);

    float s8[8];
#pragma unroll
    for (int i = 0; i < 8; ++i)
      s8[i] = (sc[0][i] + sc[0][i + 8]) + (sc[1][i] + sc[1][i + 8]);
#pragma unroll
    for (int i = 0; i < 4; ++i) s8[i] += s8[i + 4];
    lrun += (s8[0] + s8[1]) + (s8[2] + s8[3]);

    short8 pf[4];
#pragma unroll
    for (int n = 0; n < 2; ++n) {
      unsigned wv[8];
#pragma unroll
      for (int Qd = 0; Qd < 4; ++Qd) {
        unsigned w0, w1;
        asm("v_cvt_pk_bf16_f32 %0, %1, %2" : "=v"(w0) : "v"(sc[n][Qd * 4 + 0]), "v"(sc[n][Qd * 4 + 1]));
        asm("v_cvt_pk_bf16_f32 %0, %1, %2" : "=v"(w1) : "v"(sc[n][Qd * 4 + 2]), "v"(sc[n][Qd * 4 + 3]));
        wv[Qd * 2] = w0; wv[Qd * 2 + 1] = w1;
      }
#pragma unroll
      for (int m = 0; m < 2; ++m) {
        u32x2 r0 = __builtin_amdgcn_permlane32_swap(wv[(2 * m) * 2 + 0], wv[(2 * m + 1) * 2 + 0], false, false);
        u32x2 r1 = __builtin_amdgcn_permlane32_swap(wv[(2 * m) * 2 + 1], wv[(2 * m + 1) * 2 + 1], false, false);
        union { unsigned u[4]; short8 s; } fu;
        fu.u[0] = r0[0]; fu.u[1] = r1[0]; fu.u[2] = r0[1]; fu.u[3] = r1[1];
        pf[n * 2 + m] = fu.s;
      }
    }

    __builtin_amdgcn_s_setprio(1);
#pragma unroll
    for (int kvb = 0; kvb < 4; ++kvb) {
      int ch = ((kvb * 2 + h) ^ qsw) * 8;
      short8 vf0 = *(const short8*)(Vc + q * 64 + ch);
      short8 vf1 = *(const short8*)(Vc + (32 + q) * 64 + ch);
      oacc[0] = __builtin_amdgcn_mfma_f32_32x32x16_bf16(vf0, pf[kvb], oacc[0], 0, 0, 0);
      oacc[1] = __builtin_amdgcn_mfma_f32_32x32x16_bf16(vf1, pf[kvb], oacc[1], 0, 0, 0);
    }
    __builtin_amdgcn_s_setprio(0);
    cur ^= 1;
  }
#undef STAGE

  const int b_ = bh >> 4, h_ = bh & 15;
  float lt = lrun;
  lt += __shfl_xor(lt, 32);
  float inv = 1.0f / lt;
  const int srow = qblk * 128 + w * 32 + q;
#pragma unroll
  for (int d = 0; d < 2; ++d)
#pragma unroll
    for (int rq = 0; rq < 4; ++rq) {
      ushort4 pk;
      pk.x = f2bf(oacc[d][rq * 4 + 0] * inv);
      pk.y = f2bf(oacc[d][rq * 4 + 1] * inv);
      pk.z = f2bf(oacc[d][rq * 4 + 2] * inv);
      pk.w = f2bf(oacc[d][rq * 4 + 3] * inv);
      size_t off = ((size_t)b_ * SS + srow) * D_MODEL + h_ * 64 + d * 32 + rq * 8 + h * 4;
      *(ushort4*)(Ob + off) = pk;
    }
}

extern "C" void kernel_launch(void* const* d_in, const int* in_sizes, int n_in,
                              void* d_out, int out_size, void* d_ws, size_t ws_size,
                              hipStream_t stream) {
  (void)in_sizes; (void)n_in; (void)out_size; (void)ws_size;
  const float* x  = (const float*)d_in[0];
  const float* wq = (const float*)d_in[1];
  const float* bq = (const float*)d_in[2];
  const float* wk = (const float*)d_in[3];
  const float* bk = (const float*)d_in[4];
  const float* wv = (const float*)d_in[5];
  const float* bv = (const float*)d_in[6];
  const float* wo = (const float*)d_in[7];
  const float* bo = (const float*)d_in[8];

  char* ws = (char*)d_ws;
  // layout (bytes): xb 16MB | wqkvt 6MB | wot 2MB | Qw 16MB | Kw 16MB | Vw 16MB
  ushort* xb    = (ushort*)(ws);
  ushort* wqkvt = (ushort*)(ws + 16777216);
  ushort* wot   = (ushort*)(ws + 16777216 + 6291456);
  ushort* Qw    = (ushort*)(ws + 16777216 + 6291456 + 2097152);
  ushort* Kw    = (ushort*)(ws + 16777216 + 6291456 + 2097152 + 16777216);
  ushort* Vw    = (ushort*)(ws + 16777216 + 6291456 + 2097152 + 2 * 16777216);
  ushort* Obw   = xb;  // xb dead after QKV projection; reuse for attention output

  convert_x_k<<<MROWS * D_MODEL / 4 / 256, 256, 0, stream>>>(x, xb);
  convert_wt4_k<<<dim3(16, 16, 4), 256, 0, stream>>>(
      wq, wk, wv, wo, wqkvt, wqkvt + 1024 * 1024, wqkvt + 2 * 1024 * 1024, wot);

  // Q pre-scaled by (1/sqrt(DK)) * log2(e) so softmax runs in exp2 domain
  gemm_qkv_k<<<768, 512, 0, stream>>>(xb, wqkvt, bq, bk, bv, Qw, Kw, Vw,
                                      0.125f * 1.44269504088896f);

  attn_k<<<1024, 256, 0, stream>>>(Qw, Kw, Vw, Obw);

  gemm_out_k<<<512, 256, 0, stream>>>(Obw, wot, bo, (float*)d_out);
}

// Round 15
// 195.420 us; speedup vs baseline: 1.0510x; 1.0015x over previous
//
#include <hip/hip_runtime.h>

#define D_MODEL 1024
#define NH 16
#define DK 64
#define BB 4
#define SS 2048
#define MROWS (BB*SS)

typedef __attribute__((ext_vector_type(4))) float f32x4;
typedef __attribute__((ext_vector_type(16))) float f32x16;
typedef __attribute__((ext_vector_type(8))) short short8;
typedef __attribute__((ext_vector_type(4))) float float4v;
typedef __attribute__((ext_vector_type(2))) unsigned u32x2;

typedef const __attribute__((address_space(1))) void* gas_t;
typedef __attribute__((address_space(3))) void* las_t;

static __device__ __forceinline__ ushort f2bf(float f) {
  union { float f; unsigned u; } v; v.f = f;
  unsigned r = 0x7fffu + ((v.u >> 16) & 1u);
  return (ushort)((v.u + r) >> 16);
}

// counted vmcnt wait + scheduling fence (rule #18)
#define VM_WAIT(N)                                              \
  do {                                                          \
    asm volatile("s_waitcnt vmcnt(" #N ")" ::: "memory");       \
    __builtin_amdgcn_sched_barrier(0);                          \
  } while (0)

#define LGKM0()                                                 \
  do {                                                          \
    asm volatile("s_waitcnt lgkmcnt(0)" ::: "memory");          \
    __builtin_amdgcn_sched_barrier(0);                          \
  } while (0)

// -------- convert x (fp32 -> bf16), grid-stride, 2048 blocks (G11) --------
__global__ __launch_bounds__(256) void convert_x_k(const float* __restrict__ x,
                                                   ushort* __restrict__ xb) {
  const int total = MROWS * D_MODEL / 4;   // float4 chunks
  for (int i = blockIdx.x * 256 + threadIdx.x; i < total; i += 2048 * 256) {
    float4v v = ((const float4v*)x)[i];
    ushort4 o;
    o.x = f2bf(v.x); o.y = f2bf(v.y); o.z = f2bf(v.z); o.w = f2bf(v.w);
    ((ushort4*)xb)[i] = o;
  }
}

// ------- transpose 4 weights [K][N] fp32 -> [N][K] bf16, one launch -------
__global__ __launch_bounds__(256) void convert_wt4_k(const float* __restrict__ w0,
                                                     const float* __restrict__ w1,
                                                     const float* __restrict__ w2,
                                                     const float* __restrict__ w3,
                                                     ushort* __restrict__ t0,
                                                     ushort* __restrict__ t1,
                                                     ushort* __restrict__ t2,
                                                     ushort* __restrict__ t3) {
  __shared__ float tile[64][65];
  const float* w; ushort* wt;
  switch (blockIdx.z) {
    case 0: w = w0; wt = t0; break;
    case 1: w = w1; wt = t1; break;
    case 2: w = w2; wt = t2; break;
    default: w = w3; wt = t3; break;
  }
  int bx = blockIdx.x, by = blockIdx.y;
  int tx = threadIdx.x & 63, ty = threadIdx.x >> 6;
#pragma unroll
  for (int i = 0; i < 16; ++i) {
    int r = i * 4 + ty;
    tile[r][tx] = w[(size_t)(by * 64 + r) * D_MODEL + bx * 64 + tx];
  }
  __syncthreads();
#pragma unroll
  for (int i = 0; i < 16; ++i) {
    int r = i * 4 + ty;
    wt[(size_t)(bx * 64 + r) * D_MODEL + by * 64 + tx] = f2bf(tile[tx][r]);
  }
}

// ------------- fused QKV GEMM: [8192,1024] x [3072,1024]^T ---------------
// 256x128 tile, BK=64, 512 thr (8 waves, 4M x 2N, 64x64 out each).
// 3-buffer LDS, 2-tile-deep prefetch, counted vmcnt (never 0 mid-loop),
// chunk-XOR swizzle (pos = chunk ^ (row&7)) on source AND read -> 0 conflicts.
__global__ __launch_bounds__(512) void gemm_qkv_k(const ushort* __restrict__ A,
                                                  const ushort* __restrict__ Bt,
                                                  const float* __restrict__ bq,
                                                  const float* __restrict__ bk,
                                                  const float* __restrict__ bv,
                                                  ushort* __restrict__ Qw,
                                                  ushort* __restrict__ Kw,
                                                  ushort* __restrict__ Vw,
                                                  float qscale) {
  const int K = D_MODEL;
  __shared__ __align__(16) ushort As[3][256 * 64];   // 3 x 32 KB
  __shared__ __align__(16) ushort Bs[3][128 * 64];   // 3 x 16 KB
  const int nbn = 24;                     // 3072/128
  int bid = blockIdx.x;
  int wg = (bid & 7) * 96 + (bid >> 3);   // XCD swizzle (768 = 8*96, bijective)
  int bm = wg / nbn, bn = wg % nbn;       // bm-major per XCD: A-panel in L2
  const int t = threadIdx.x;
  const int l = t & 63;
  const int w = t >> 6;                   // 0..7
  const int g = l >> 4, q = l & 15;
  const int wr = w >> 1, wc = w & 1;      // 4 M-warps x 2 N-warps
  const int qs = q & 7;

  f32x4 acc[4][4];
#pragma unroll
  for (int m = 0; m < 4; ++m)
#pragma unroll
    for (int n = 0; n < 4; ++n) acc[m][n] = f32x4{0.f, 0.f, 0.f, 0.f};

  const ushort* Ab = A + (size_t)bm * 256 * K;
  const ushort* Bb = Bt + (size_t)bn * 128 * K;

#define GSTAGE(BUF, KT)                                                                       \
  do {                                                                                        \
    _Pragma("unroll") for (int i_ = 0; i_ < 4; ++i_) {                                        \
      int c_ = i_ * 512 + t;                                                                  \
      int r_ = c_ >> 3;                                                                       \
      int gc_ = (c_ & 7) ^ (r_ & 7);                                                          \
      __builtin_amdgcn_global_load_lds((gas_t)(Ab + (size_t)r_ * K + (KT) * 64 + gc_ * 8),    \
                                       (las_t)(&As[BUF][c_ * 8]), 16, 0, 0);                  \
    }                                                                                         \
    _Pragma("unroll") for (int i_ = 0; i_ < 2; ++i_) {                                        \
      int c_ = i_ * 512 + t;                                                                  \
      int r_ = c_ >> 3;                                                                       \
      int gc_ = (c_ & 7) ^ (r_ & 7);                                                          \
      __builtin_amdgcn_global_load_lds((gas_t)(Bb + (size_t)r_ * K + (KT) * 64 + gc_ * 8),    \
                                       (las_t)(&Bs[BUF][c_ * 8]), 16, 0, 0);                  \
    }                                                                                         \
  } while (0)

  GSTAGE(0, 0);
  GSTAGE(1, 1);

  for (int kt = 0; kt < 16; ++kt) {
    if (kt + 2 < 16) {
      GSTAGE((kt + 2) % 3, kt + 2);
      VM_WAIT(12);                     // t+1, t+2 in flight; tile kt landed
    } else if (kt + 1 < 16) {
      VM_WAIT(6);
    } else {
      VM_WAIT(0);
    }
    __builtin_amdgcn_s_barrier();
    __builtin_amdgcn_sched_barrier(0);

    const ushort* Ac = As[kt % 3];
    const ushort* Bc = Bs[kt % 3];

    short8 bf[4][2];
#pragma unroll
    for (int n = 0; n < 4; ++n)
#pragma unroll
      for (int ks = 0; ks < 2; ++ks)
        bf[n][ks] = *(const short8*)(Bc + (wc * 64 + n * 16 + q) * 64 + (((ks * 4 + g) ^ qs) * 8));

#pragma unroll
    for (int mh = 0; mh < 2; ++mh) {
      short8 af[2][2];
#pragma unroll
      for (int m2 = 0; m2 < 2; ++m2)
#pragma unroll
        for (int ks = 0; ks < 2; ++ks)
          af[m2][ks] = *(const short8*)(Ac + (wr * 64 + (mh * 2 + m2) * 16 + q) * 64 + (((ks * 4 + g) ^ qs) * 8));
      LGKM0();
      __builtin_amdgcn_s_setprio(1);
#pragma unroll
      for (int m2 = 0; m2 < 2; ++m2)
#pragma unroll
        for (int n = 0; n < 4; ++n)
#pragma unroll
          for (int ks = 0; ks < 2; ++ks)
            acc[mh * 2 + m2][n] =
                __builtin_amdgcn_mfma_f32_16x16x32_bf16(af[m2][ks], bf[n][ks], acc[mh * 2 + m2][n], 0, 0, 0);
      __builtin_amdgcn_s_setprio(0);
    }

    __builtin_amdgcn_sched_barrier(0);
    __builtin_amdgcn_s_barrier();      // protect buf[(kt+3)%3] == buf[kt%3] restage
  }
#undef GSTAGE

  const int sec = (bn * 128) >> 10;            // 0=Q 1=K 2=V
  const float* bias = sec == 0 ? bq : (sec == 1 ? bk : bv);
  const float scale = sec == 0 ? qscale : 1.0f;
  ushort* dst = sec == 0 ? Qw : Kw;
  const int rbase0 = bm * 256 + wr * 64 + g * 4;
  const int cbase = (bn * 128 + wc * 64 + q) & 1023;
#pragma unroll
  for (int m = 0; m < 4; ++m) {
    int r0 = rbase0 + m * 16;
#pragma unroll
    for (int n = 0; n < 4; ++n) {
      int c = cbase + n * 16;
      float bv_ = bias[c];
      if (sec == 2) {
        ushort4 pk;
        pk.x = f2bf(acc[m][n][0] + bv_);
        pk.y = f2bf(acc[m][n][1] + bv_);
        pk.z = f2bf(acc[m][n][2] + bv_);
        pk.w = f2bf(acc[m][n][3] + bv_);
        size_t off = (((size_t)((r0 >> 11) * NH + (c >> 6))) * DK + (c & 63)) * (size_t)SS + (r0 & (SS - 1));
        *(ushort4*)(Vw + off) = pk;
      } else {
#pragma unroll
        for (int j = 0; j < 4; ++j) {
          int r = r0 + j;
          float v = (acc[m][n][j] + bv_) * scale;
          size_t off = (((size_t)((r >> 11) * NH + (c >> 6))) * SS + (r & (SS - 1))) * DK + (c & 63);
          dst[off] = f2bf(v);
        }
      }
    }
  }
}

// ------------- output GEMM: [8192,1024] x [1024,1024]^T -> fp32 ----------
__global__ __launch_bounds__(256) void gemm_out_k(const ushort* __restrict__ A,
                                                  const ushort* __restrict__ Bt,
                                                  const float* __restrict__ bias,
                                                  float* __restrict__ outp) {
  const int K = D_MODEL;
  __shared__ __align__(16) ushort As[2][128 * 32];
  __shared__ __align__(16) ushort Bs[2][128 * 32];
  const int nbn = 8;
  int bid = blockIdx.x;
  int wg = (bid & 7) * 64 + (bid >> 3);
  int bm = wg / nbn, bn = wg % nbn;
  const int t = threadIdx.x;
  const int l = t & 63;
  const int w = t >> 6;
  const int g = l >> 4, q = l & 15;
  const int wr = w >> 1, wc = w & 1;

  f32x4 acc[4][4];
#pragma unroll
  for (int m = 0; m < 4; ++m)
#pragma unroll
    for (int n = 0; n < 4; ++n) acc[m][n] = f32x4{0.f, 0.f, 0.f, 0.f};

  const ushort* Ab = A + (size_t)bm * 128 * K;
  const ushort* Bb = Bt + (size_t)bn * 128 * K;

#define GSTAGE(BUF, KT)                                                                      \
  do {                                                                                       \
    _Pragma("unroll") for (int i_ = 0; i_ < 2; ++i_) {                                       \
      int c_ = i_ * 256 + t;                                                                 \
      __builtin_amdgcn_global_load_lds((gas_t)(Ab + (size_t)(c_ >> 2) * K + (KT) + (c_ & 3) * 8), \
                                       (las_t)(As[BUF] + c_ * 8), 16, 0, 0);                 \
      __builtin_amdgcn_global_load_lds((gas_t)(Bb + (size_t)(c_ >> 2) * K + (KT) + (c_ & 3) * 8), \
                                       (las_t)(Bs[BUF] + c_ * 8), 16, 0, 0);                 \
    }                                                                                        \
  } while (0)

  GSTAGE(0, 0);
  int cur = 0;

  for (int kt = 0; kt < K; kt += 32) {
    if (kt + 32 < K) {
      GSTAGE(cur ^ 1, kt + 32);
      VM_WAIT(4);
    } else {
      VM_WAIT(0);
    }
    __builtin_amdgcn_s_barrier();
    __builtin_amdgcn_sched_barrier(0);
    short8 af[4], bf[4];
#pragma unroll
    for (int m = 0; m < 4; ++m)
      af[m] = *(const short8*)(As[cur] + (wr * 64 + m * 16 + q) * 32 + g * 8);
#pragma unroll
    for (int n = 0; n < 4; ++n)
      bf[n] = *(const short8*)(Bs[cur] + (wc * 64 + n * 16 + q) * 32 + g * 8);
#pragma unroll
    for (int m = 0; m < 4; ++m)
#pragma unroll
      for (int n = 0; n < 4; ++n)
        acc[m][n] = __builtin_amdgcn_mfma_f32_16x16x32_bf16(af[m], bf[n], acc[m][n], 0, 0, 0);
    __builtin_amdgcn_sched_barrier(0);
    __builtin_amdgcn_s_barrier();
    cur ^= 1;
  }
#undef GSTAGE

  const int rbase0 = bm * 128 + wr * 64 + g * 4;
  const int cbase = bn * 128 + wc * 64 + q;
#pragma unroll
  for (int m = 0; m < 4; ++m) {
    int r0 = rbase0 + m * 16;
#pragma unroll
    for (int n = 0; n < 4; ++n) {
      int c = cbase + n * 16;
      float bv = bias[c];
#pragma unroll
      for (int j = 0; j < 4; ++j)
        outp[(size_t)(r0 + j) * D_MODEL + c] = acc[m][n][j] + bv;
    }
  }
}

// ---------------- flash attention, 32x32 swapped-operand, 32q/wave --------
__global__ __launch_bounds__(256, 4) void attn_k(const ushort* __restrict__ Qm,
                                                 const ushort* __restrict__ Km,
                                                 const ushort* __restrict__ Vm,
                                                 ushort* __restrict__ Ob) {
  __shared__ __align__(16) ushort Ks[2][64 * 64];   // [buf][kv][dk] chunk-XOR-swizzled
  __shared__ __align__(16) ushort Vs[2][64 * 64];   // [buf][d][kv]  chunk-XOR-swizzled
  const int bid = blockIdx.x;
  const int logical = (bid & 7) * 128 + (bid >> 3); // XCD chunk swizzle (1024 = 8*128)
  const int bh = logical >> 4;       // 0..63
  const int qblk = logical & 15;     // 0..15 (128 q-rows/block, 32/wave)
  const int t = threadIdx.x, l = t & 63, w = t >> 6;
  const int q = l & 31, h = l >> 5;
  const int qsw = q & 7;

  const ushort* Qb = Qm + ((size_t)bh * SS + qblk * 128 + w * 32) * DK;
  const ushort* Kb = Km + (size_t)bh * SS * DK;
  const ushort* Vb = Vm + (size_t)bh * DK * SS;

  short8 qf[4];
#pragma unroll
  for (int ks = 0; ks < 4; ++ks)
    qf[ks] = *(const short8*)(Qb + q * DK + ks * 16 + h * 8);

  f32x16 oacc[2];
#pragma unroll
  for (int d = 0; d < 2; ++d)
#pragma unroll
    for (int r = 0; r < 16; ++r) oacc[d][r] = 0.f;
  float lrun = 0.f;

  const int cg = (l & 7) ^ ((l >> 3) & 7);

#define STAGE(B, KT)                                                                        \
  do {                                                                                      \
    _Pragma("unroll") for (int i_ = 0; i_ < 2; ++i_) {                                      \
      int row_ = w * 16 + i_ * 8 + (l >> 3);                                                \
      __builtin_amdgcn_global_load_lds((gas_t)(Kb + (size_t)((KT) + row_) * DK + cg * 8),   \
                                       (las_t)(Ks[B] + (w * 16 + i_ * 8) * 64 + l * 8),     \
                                       16, 0, 0);                                           \
      __builtin_amdgcn_global_load_lds((gas_t)(Vb + (size_t)row_ * SS + (KT) + cg * 8),     \
                                       (las_t)(Vs[B] + (w * 16 + i_ * 8) * 64 + l * 8),     \
                                       16, 0, 0);                                           \
    }                                                                                       \
  } while (0)

  STAGE(0, 0);
  int cur = 0;

  for (int kt = 0; kt < SS; kt += 64) {
    __syncthreads();
    if (kt + 64 < SS) STAGE(cur ^ 1, kt + 64);

    const ushort* Kc = Ks[cur];
    const ushort* Vc = Vs[cur];

    f32x16 sc[2];
#pragma unroll
    for (int n = 0; n < 2; ++n)
#pragma unroll
      for (int r = 0; r < 16; ++r) sc[n][r] = 0.f;

    __builtin_amdgcn_s_setprio(1);
#pragma unroll
    for (int ks = 0; ks < 4; ++ks) {
      int ch = ((ks * 2 + h) ^ qsw) * 8;
      short8 kf0 = *(const short8*)(Kc + q * 64 + ch);
      short8 kf1 = *(const short8*)(Kc + (32 + q) * 64 + ch);
      sc[0] = __builtin_amdgcn_mfma_f32_32x32x16_bf16(kf0, qf[ks], sc[0], 0, 0, 0);
      sc[1] = __builtin_amdgcn_mfma_f32_32x32x16_bf16(kf1, qf[ks], sc[1], 0, 0, 0);
    }
    __builtin_amdgcn_s_setprio(0);

#pragma unroll
    for (int n = 0; n < 2; ++n)
#pragma unroll
      for (int r = 0; r < 16; ++r) sc[n][r] = __builtin_amdgcn_exp2f(sc[n][r]);

    float s8[8];
#pragma unroll
    for (int i = 0; i < 8; ++i)
      s8[i] = (sc[0][i] + sc[0][i + 8]) + (sc[1][i] + sc[1][i + 8]);
#pragma unroll
    for (int i = 0; i < 4; ++i) s8[i] += s8[i + 4];
    lrun += (s8[0] + s8[1]) + (s8[2] + s8[3]);

    short8 pf[4];
#pragma unroll
    for (int n = 0; n < 2; ++n) {
      unsigned wv[8];
#pragma unroll
      for (int Qd = 0; Qd < 4; ++Qd) {
        unsigned w0, w1;
        asm("v_cvt_pk_bf16_f32 %0, %1, %2" : "=v"(w0) : "v"(sc[n][Qd * 4 + 0]), "v"(sc[n][Qd * 4 + 1]));
        asm("v_cvt_pk_bf16_f32 %0, %1, %2" : "=v"(w1) : "v"(sc[n][Qd * 4 + 2]), "v"(sc[n][Qd * 4 + 3]));
        wv[Qd * 2] = w0; wv[Qd * 2 + 1] = w1;
      }
#pragma unroll
      for (int m = 0; m < 2; ++m) {
        u32x2 r0 = __builtin_amdgcn_permlane32_swap(wv[(2 * m) * 2 + 0], wv[(2 * m + 1) * 2 + 0], false, false);
        u32x2 r1 = __builtin_amdgcn_permlane32_swap(wv[(2 * m) * 2 + 1], wv[(2 * m + 1) * 2 + 1], false, false);
        union { unsigned u[4]; short8 s; } fu;
        fu.u[0] = r0[0]; fu.u[1] = r1[0]; fu.u[2] = r0[1]; fu.u[3] = r1[1];
        pf[n * 2 + m] = fu.s;
      }
    }

    __builtin_amdgcn_s_setprio(1);
#pragma unroll
    for (int kvb = 0; kvb < 4; ++kvb) {
      int ch = ((kvb * 2 + h) ^ qsw) * 8;
      short8 vf0 = *(const short8*)(Vc + q * 64 + ch);
      short8 vf1 = *(const short8*)(Vc + (32 + q) * 64 + ch);
      oacc[0] = __builtin_amdgcn_mfma_f32_32x32x16_bf16(vf0, pf[kvb], oacc[0], 0, 0, 0);
      oacc[1] = __builtin_amdgcn_mfma_f32_32x32x16_bf16(vf1, pf[kvb], oacc[1], 0, 0, 0);
    }
    __builtin_amdgcn_s_setprio(0);
    cur ^= 1;
  }
#undef STAGE

  const int b_ = bh >> 4, h_ = bh & 15;
  float lt = lrun;
  lt += __shfl_xor(lt, 32);
  float inv = 1.0f / lt;
  const int srow = qblk * 128 + w * 32 + q;
#pragma unroll
  for (int d = 0; d < 2; ++d)
#pragma unroll
    for (int rq = 0; rq < 4; ++rq) {
      ushort4 pk;
      pk.x = f2bf(oacc[d][rq * 4 + 0] * inv);
      pk.y = f2bf(oacc[d][rq * 4 + 1] * inv);
      pk.z = f2bf(oacc[d][rq * 4 + 2] * inv);
      pk.w = f2bf(oacc[d][rq * 4 + 3] * inv);
      size_t off = ((size_t)b_ * SS + srow) * D_MODEL + h_ * 64 + d * 32 + rq * 8 + h * 4;
      *(ushort4*)(Ob + off) = pk;
    }
}

extern "C" void kernel_launch(void* const* d_in, const int* in_sizes, int n_in,
                              void* d_out, int out_size, void* d_ws, size_t ws_size,
                              hipStream_t stream) {
  (void)in_sizes; (void)n_in; (void)out_size; (void)ws_size;
  const float* x  = (const float*)d_in[0];
  const float* wq = (const float*)d_in[1];
  const float* bq = (const float*)d_in[2];
  const float* wk = (const float*)d_in[3];
  const float* bk = (const float*)d_in[4];
  const float* wv = (const float*)d_in[5];
  const float* bv = (const float*)d_in[6];
  const float* wo = (const float*)d_in[7];
  const float* bo = (const float*)d_in[8];

  char* ws = (char*)d_ws;
  // layout (bytes): xb 16MB | wqkvt 6MB | wot 2MB | Qw 16MB | Kw 16MB | Vw 16MB
  ushort* xb    = (ushort*)(ws);
  ushort* wqkvt = (ushort*)(ws + 16777216);
  ushort* wot   = (ushort*)(ws + 16777216 + 6291456);
  ushort* Qw    = (ushort*)(ws + 16777216 + 6291456 + 2097152);
  ushort* Kw    = (ushort*)(ws + 16777216 + 6291456 + 2097152 + 16777216);
  ushort* Vw    = (ushort*)(ws + 16777216 + 6291456 + 2097152 + 2 * 16777216);
  ushort* Obw   = xb;  // xb dead after QKV projection; reuse for attention output

  convert_x_k<<<2048, 256, 0, stream>>>(x, xb);
  convert_wt4_k<<<dim3(16, 16, 4), 256, 0, stream>>>(
      wq, wk, wv, wo, wqkvt, wqkvt + 1024 * 1024, wqkvt + 2 * 1024 * 1024, wot);

  // Q pre-scaled by (1/sqrt(DK)) * log2(e) so softmax runs in exp2 domain
  gemm_qkv_k<<<768, 512, 0, stream>>>(xb, wqkvt, bq, bk, bv, Qw, Kw, Vw,
                                      0.125f * 1.44269504088896f);

  attn_k<<<1024, 256, 0, stream>>>(Qw, Kw, Vw, Obw);

  gemm_out_k<<<512, 256, 0, stream>>>(Obw, wot, bo, (float*)d_out);
}